// Round 1
// baseline (1445.645 us; speedup 1.0000x reference)
//
#include <hip/hip_runtime.h>
#include <cstdint>
#include <cstddef>

// ---------------------------------------------------------------------------
// SwinV2 block, MI355X bf16-MFMA implementation.
// Sizes: B=32, H=W=56, WS=7, N=49, NW=64, HEADS=12, DIM=384, tokens M=100352.
// A/B frag layout for v_mfma_f32_16x16x32_bf16: contiguous-8
//   (lane holds A[l&15][8*(l>>4)+i]); flip AB_TWOHALF to 1 for the
//   two-half variant (k = 16*(i>>2) + 4*(l>>4) + (i&3)) if refcheck fails.
// ---------------------------------------------------------------------------

#ifndef AB_TWOHALF
#define AB_TWOHALF 0
#endif

typedef unsigned short u16;
typedef __bf16 bf16x8 __attribute__((ext_vector_type(8)));
typedef __bf16 bf16x4 __attribute__((ext_vector_type(4)));
typedef float f32x4 __attribute__((ext_vector_type(4)));

__device__ __forceinline__ u16 f2bf(float f) {
  unsigned u = __builtin_bit_cast(unsigned, f);
  u += 0x7fffu + ((u >> 16) & 1u);
  return (u16)(u >> 16);
}

// load one 8-elem MFMA input fragment; rowp = &LDS[row*ld + k_base], l4 = lane>>4
__device__ __forceinline__ bf16x8 ldfrag(const u16* rowp, int l4) {
#if AB_TWOHALF
  bf16x4 lo = *(const bf16x4*)(rowp + 4 * l4);
  bf16x4 hi = *(const bf16x4*)(rowp + 16 + 4 * l4);
  bf16x8 r;
  r[0]=lo[0]; r[1]=lo[1]; r[2]=lo[2]; r[3]=lo[3];
  r[4]=hi[0]; r[5]=hi[1]; r[6]=hi[2]; r[7]=hi[3];
  return r;
#else
  return *(const bf16x8*)(rowp + 8 * l4);
#endif
}

// ---------------- diagnostics: ws too small sentinel ----------------
__global__ __launch_bounds__(256) void fill_k(float* o, int n) {
  int i = blockIdx.x * 256 + threadIdx.x;
  if (i < n) o[i] = 12345.0f;
}

// ---------------- weight convert + transpose (fp32 [K][N] -> bf16 [N][K]) ----
__global__ __launch_bounds__(256) void wconv_k(
    const float* __restrict__ qkv_w, const float* __restrict__ proj_w,
    const float* __restrict__ mlp_w1, const float* __restrict__ mlp_w2,
    u16* __restrict__ o) {
  const int id = blockIdx.x * 256 + threadIdx.x;  // grid covers exactly 1769472
  if (id < 442368) {                // qkv_w (384,1152) -> [1152][384]
    const int n = id / 384, k = id - n * 384;
    o[id] = f2bf(qkv_w[k * 1152 + n]);
  } else if (id < 589824) {         // proj_w (384,384) -> [384][384]
    const int e = id - 442368; const int n = e / 384, k = e - n * 384;
    o[id] = f2bf(proj_w[k * 384 + n]);
  } else if (id < 1179648) {        // mlp_w1 (384,1536) -> [1536][384]
    const int e = id - 589824; const int n = e / 384, k = e - n * 384;
    o[id] = f2bf(mlp_w1[k * 1536 + n]);
  } else {                          // mlp_w2 (1536,384) -> [384][1536]
    const int e = id - 1179648; const int n = e / 1536, k = e - n * 1536;
    o[id] = f2bf(mlp_w2[k * 384 + n]);
  }
}

// ---------------- continuous relative position bias table -------------------
// biasT[h][i][j], h<12, i,j<49
__global__ __launch_bounds__(256) void biastab_k(
    const float* __restrict__ w1, const float* __restrict__ b1,
    const float* __restrict__ w2, const float* __restrict__ b2,
    float* __restrict__ biasT) {
  const int id = blockIdx.x * 256 + threadIdx.x;
  if (id >= 2401) return;
  const int i = id / 49, j = id - i * 49;
  const int r1 = i / 7, c1 = i - r1 * 7, r2 = j / 7, c2 = j - r2 * 7;
  float dy = (float)(r1 - r2), dx = (float)(c1 - c2);
  dy = copysignf(log1pf(fabsf(dy)), dy);
  dx = copysignf(log1pf(fabsf(dx)), dx);
  float accv[12];
#pragma unroll
  for (int t = 0; t < 12; ++t) accv[t] = b2[t];
  for (int u = 0; u < 64; ++u) {
    float hu = fmaxf(dy * w1[u] + dx * w1[64 + u] + b1[u], 0.0f);
#pragma unroll
    for (int t = 0; t < 12; ++t) accv[t] += hu * w2[u * 12 + t];
  }
#pragma unroll
  for (int t = 0; t < 12; ++t) biasT[t * 2401 + id] = accv[t];
}

// ---------------- LayerNorm (one wave per token), optional shift+window map --
template <int WINMAP>
__global__ __launch_bounds__(256, 4) void ln_k(
    const float* __restrict__ X, const float* __restrict__ g,
    const float* __restrict__ b, u16* __restrict__ O) {
  const int t = blockIdx.x * 4 + (threadIdx.x >> 6);
  const int lane = threadIdx.x & 63;
  const float* xr = X + (size_t)t * 384;
  float v[6];
  float s = 0.f;
#pragma unroll
  for (int i = 0; i < 6; ++i) { v[i] = xr[lane + i * 64]; s += v[i]; }
#pragma unroll
  for (int m = 1; m < 64; m <<= 1) s += __shfl_xor(s, m);
  const float mu = s * (1.0f / 384.0f);
  float q = 0.f;
#pragma unroll
  for (int i = 0; i < 6; ++i) { float d = v[i] - mu; q += d * d; }
#pragma unroll
  for (int m = 1; m < 64; m <<= 1) q += __shfl_xor(q, m);
  const float rstd = rsqrtf(q * (1.0f / 384.0f) + 1e-5f);
  size_t row;
  if constexpr (WINMAP) {
    const int bb = t / 3136, hw = t - bb * 3136;
    const int ho = hw / 56, wo = hw - ho * 56;
    int hs = ho - 3; if (hs < 0) hs += 56;
    int ws2 = wo - 3; if (ws2 < 0) ws2 += 56;
    const int h7 = hs / 7, w7 = ws2 / 7;
    const int wwin = bb * 64 + h7 * 8 + w7;
    const int p = (hs - h7 * 7) * 7 + (ws2 - w7 * 7);
    row = (size_t)wwin * 49 + p;
  } else {
    row = (size_t)t;
  }
  u16* orow = O + row * 384;
#pragma unroll
  for (int i = 0; i < 6; ++i) {
    const int d = lane + i * 64;
    orow[d] = f2bf((v[i] - mu) * rstd * g[d] + b[d]);
  }
}

// ---------------- generic 128x128 bf16 MFMA GEMM with fused epilogues --------
// A [M][K] bf16 row-major, Bt [N][K] bf16 row-major (i.e. W transposed).
// EPI 0: qkv   (bias add, q/k head L2-norm, tau fold into q) -> bf16 out
// EPI 1: proj  (bias + residual x + window-reverse/unshift)  -> f32 d_out
// EPI 2: mlp1  (bias + exact gelu)                           -> bf16 out
// EPI 3: mlp2  (bias, accumulate into d_out)                 -> f32 +=
template <int EPI>
__global__ __launch_bounds__(256, 2) void gemm_k(
    const u16* __restrict__ A, const u16* __restrict__ Bt,
    const float* __restrict__ bias, const float* __restrict__ aux,
    void* __restrict__ outp, int M, int N, int K) {
  __shared__ u16 Ash[128 * 32];
  __shared__ u16 Bsh[128 * 32];
  const int tid = threadIdx.x;
  const int lane = tid & 63;
  const int wid = tid >> 6;
  const int wrow = wid >> 1, wcol = wid & 1;
  const int l15 = lane & 15, l4 = lane >> 4;
  const int tileM = blockIdx.y * 128;
  const int tileN = blockIdx.x * 128;

  f32x4 acc[4][4] = {};

  const int srow = tid >> 2;            // 0..63
  const int scol = (tid & 3) * 8;       // 0,8,16,24

  for (int k0 = 0; k0 < K; k0 += 32) {
    uint4 a0 = *(const uint4*)(A + (size_t)(tileM + srow) * K + k0 + scol);
    uint4 a1 = *(const uint4*)(A + (size_t)(tileM + 64 + srow) * K + k0 + scol);
    uint4 b0 = *(const uint4*)(Bt + (size_t)(tileN + srow) * K + k0 + scol);
    uint4 b1 = *(const uint4*)(Bt + (size_t)(tileN + 64 + srow) * K + k0 + scol);
    __syncthreads();  // previous iter's fragment reads must finish
    *(uint4*)&Ash[srow * 32 + scol] = a0;
    *(uint4*)&Ash[(64 + srow) * 32 + scol] = a1;
    *(uint4*)&Bsh[srow * 32 + scol] = b0;
    *(uint4*)&Bsh[(64 + srow) * 32 + scol] = b1;
    __syncthreads();
    bf16x8 af[4], bfr[4];
#pragma unroll
    for (int f = 0; f < 4; ++f) {
      af[f] = ldfrag(&Ash[(wrow * 64 + f * 16 + l15) * 32], l4);
      bfr[f] = ldfrag(&Bsh[(wcol * 64 + f * 16 + l15) * 32], l4);
    }
#pragma unroll
    for (int fm = 0; fm < 4; ++fm)
#pragma unroll
      for (int fn = 0; fn < 4; ++fn)
        acc[fm][fn] = __builtin_amdgcn_mfma_f32_16x16x32_bf16(
            af[fm], bfr[fn], acc[fm][fn], 0, 0, 0);
  }

  const int baseRow = tileM + wrow * 64;
  const int baseCol = tileN + wcol * 64;

  if constexpr (EPI == 0) {
    u16* O = (u16*)outp;
#pragma unroll
    for (int fm = 0; fm < 4; ++fm) {
#pragma unroll
      for (int hp = 0; hp < 2; ++hp) {
        const int c0 = baseCol + hp * 32;
        const int seg = c0 >> 5;             // 0..11 q, 12..23 k, 24..35 v
        const bool nrm = seg < 24;
        const float tfac = (seg < 12) ? aux[seg] : 1.0f;
        const float b0 = bias[c0 + l15];
        const float b1 = bias[c0 + 16 + l15];
#pragma unroll
        for (int r = 0; r < 4; ++r) {
          float v0 = acc[fm][2 * hp][r] + b0;
          float v1 = acc[fm][2 * hp + 1][r] + b1;
          if (nrm) {
            float ss = v0 * v0 + v1 * v1;
            ss += __shfl_xor(ss, 1);
            ss += __shfl_xor(ss, 2);
            ss += __shfl_xor(ss, 4);
            ss += __shfl_xor(ss, 8);
            const float f = tfac / fmaxf(sqrtf(ss), 1e-12f);
            v0 *= f; v1 *= f;
          }
          const size_t row = (size_t)(baseRow + fm * 16 + l4 * 4 + r);
          O[row * N + c0 + l15] = f2bf(v0);
          O[row * N + c0 + 16 + l15] = f2bf(v1);
        }
      }
    }
  } else if constexpr (EPI == 1) {
    float* O = (float*)outp;
    const float* X = aux;
#pragma unroll
    for (int fm = 0; fm < 4; ++fm) {
#pragma unroll
      for (int r = 0; r < 4; ++r) {
        const int row = baseRow + fm * 16 + l4 * 4 + r;
        const int w = row / 49, p = row - w * 49;
        const int bb = w >> 6, widx = w & 63;
        const int p7 = p / 7;
        int hs = (widx >> 3) * 7 + p7;
        int ws2 = (widx & 7) * 7 + (p - p7 * 7);
        int ho = hs + 3; if (ho >= 56) ho -= 56;
        int wo = ws2 + 3; if (wo >= 56) wo -= 56;
        const size_t tok = (size_t)bb * 3136 + ho * 56 + wo;
#pragma unroll
        for (int fn = 0; fn < 4; ++fn) {
          const int col = baseCol + fn * 16 + l15;
          O[tok * 384 + col] = X[tok * 384 + col] + acc[fm][fn][r] + bias[col];
        }
      }
    }
  } else if constexpr (EPI == 2) {
    u16* O = (u16*)outp;
#pragma unroll
    for (int fm = 0; fm < 4; ++fm) {
#pragma unroll
      for (int fn = 0; fn < 4; ++fn) {
        const int col = baseCol + fn * 16 + l15;
        const float bc = bias[col];
#pragma unroll
        for (int r = 0; r < 4; ++r) {
          const size_t row = (size_t)(baseRow + fm * 16 + l4 * 4 + r);
          const float v = acc[fm][fn][r] + bc;
          const float g = 0.5f * v * (1.0f + erff(v * 0.70710678118654752f));
          O[row * N + col] = f2bf(g);
        }
      }
    }
  } else {
    float* O = (float*)outp;
#pragma unroll
    for (int fm = 0; fm < 4; ++fm) {
#pragma unroll
      for (int fn = 0; fn < 4; ++fn) {
        const int col = baseCol + fn * 16 + l15;
        const float bc = bias[col];
#pragma unroll
        for (int r = 0; r < 4; ++r) {
          const size_t row = (size_t)(baseRow + fm * 16 + l4 * 4 + r);
          O[row * N + col] += acc[fm][fn][r] + bc;
        }
      }
    }
  }
}

// ---------------- attention: one wave per (window, head) ---------------------
// qkv [M][1152] bf16 (q/k pre-normalized, tau folded into q), biasT [12][49][49]
// out [M][384] bf16, window-token order.
__global__ __launch_bounds__(256, 2) void attn_k(
    const u16* __restrict__ qkv, const float* __restrict__ biasT,
    u16* __restrict__ outp) {
  // per-wave LDS (u16 offsets): Q 64x40 @0, K 64x40 @2560, P(64x72) overlays @0,
  // VT 32x72 @5120, sums f32[64] @7424; total 7552 u16 = 15104 B
  __shared__ u16 lds[4][7552];
  const int tid = threadIdx.x, lane = tid & 63, wid = tid >> 6;
  const int l15 = lane & 15, l4 = lane >> 4;
  const int W = blockIdx.x * 4 + wid;
  const int w = W / 12, h = W - w * 12;
  u16* S = lds[wid];
  u16* Q = S;
  u16* Kl = S + 2560;
  u16* P = S;
  u16* VT = S + 5120;
  float* sums = (float*)(S + 7424);
  const u16* base = qkv + (size_t)w * 56448 + h * 32;  // 49*1152
  const int widx = w & 63, wh = widx >> 3, ww = widx & 7;
  const bool masked = (wh == 7) || (ww == 7);

  // ---- stage q, k (64 rows, zero-padded past 49) ----
#pragma unroll
  for (int it = 0; it < 4; ++it) {
    const int row = it * 16 + (lane >> 2);
    const int c8 = (lane & 3) * 8;
    uint4 qv = {0, 0, 0, 0}, kv = {0, 0, 0, 0};
    if (row < 49) {
      qv = *(const uint4*)(base + (size_t)row * 1152 + c8);
      kv = *(const uint4*)(base + (size_t)row * 1152 + 384 + c8);
    }
    *(uint4*)&Q[row * 40 + c8] = qv;
    *(uint4*)&Kl[row * 40 + c8] = kv;
  }
  // ---- stage V transposed: VT[d][j] = v[j][d] ----
  {
    const int d = lane & 31;
    const int jh = lane >> 5;
#pragma unroll 4
    for (int jt = 0; jt < 32; ++jt) {
      const int j = jt * 2 + jh;
      u16 val = 0;
      if (j < 49) val = base[(size_t)j * 1152 + 768 + d];
      VT[d * 72 + j] = val;
    }
  }
  __syncthreads();

  // ---- scores: S = Q . K^T  (64x64, K-dim 32) ----
  f32x4 sc[4][4] = {};
  {
    bf16x8 aq[4], bk[4];
#pragma unroll
    for (int f = 0; f < 4; ++f) aq[f] = ldfrag(&Q[(f * 16 + l15) * 40], l4);
#pragma unroll
    for (int f = 0; f < 4; ++f) bk[f] = ldfrag(&Kl[(f * 16 + l15) * 40], l4);
#pragma unroll
    for (int fm = 0; fm < 4; ++fm)
#pragma unroll
      for (int fn = 0; fn < 4; ++fn)
        sc[fm][fn] = __builtin_amdgcn_mfma_f32_16x16x32_bf16(
            aq[fm], bk[fn], sc[fm][fn], 0, 0, 0);
  }
  __syncthreads();  // Q/K reads complete before P overlays them

  // ---- bias + mask + softmax, P -> LDS (bf16, unnormalized), sums -> LDS ----
  int codej[4] = {0, 0, 0, 0};
  if (masked) {
#pragma unroll
    for (int fn = 0; fn < 4; ++fn) {
      const int j = fn * 16 + l15;
      const int pr = j / 7, pc = j - pr * 7;
      const int rr2 = (wh == 7) ? ((pr < 4) ? 1 : 2) : 0;
      const int cc2 = (ww == 7) ? ((pc < 4) ? 1 : 2) : 0;
      codej[fn] = rr2 * 3 + cc2;
    }
  }
#pragma unroll
  for (int fm = 0; fm < 4; ++fm) {
#pragma unroll
    for (int r = 0; r < 4; ++r) {
      const int i = fm * 16 + l4 * 4 + r;
      const bool iok = i < 49;
      int ci = 0;
      if (masked && iok) {
        const int pr = i / 7, pc = i - pr * 7;
        const int rr2 = (wh == 7) ? ((pr < 4) ? 1 : 2) : 0;
        const int cc2 = (ww == 7) ? ((pc < 4) ? 1 : 2) : 0;
        ci = rr2 * 3 + cc2;
      }
      const float* brow = biasT + (size_t)h * 2401 + (iok ? i : 0) * 49;
      float sv[4];
#pragma unroll
      for (int fn = 0; fn < 4; ++fn) {
        const int j = fn * 16 + l15;
        float s = sc[fm][fn][r];
        if (iok && j < 49) {
          s += brow[j];
          if (masked && codej[fn] != ci) s -= 100.0f;
        } else {
          s = -1e30f;
        }
        sv[fn] = s;
      }
      float mx = fmaxf(fmaxf(sv[0], sv[1]), fmaxf(sv[2], sv[3]));
      mx = fmaxf(mx, __shfl_xor(mx, 1));
      mx = fmaxf(mx, __shfl_xor(mx, 2));
      mx = fmaxf(mx, __shfl_xor(mx, 4));
      mx = fmaxf(mx, __shfl_xor(mx, 8));
      float sm = 0.f;
      u16 pb[4];
#pragma unroll
      for (int fn = 0; fn < 4; ++fn) {
        const float e = __expf(sv[fn] - mx);
        sm += e;
        pb[fn] = f2bf(e);
      }
      sm += __shfl_xor(sm, 1);
      sm += __shfl_xor(sm, 2);
      sm += __shfl_xor(sm, 4);
      sm += __shfl_xor(sm, 8);
#pragma unroll
      for (int fn = 0; fn < 4; ++fn) P[i * 72 + fn * 16 + l15] = pb[fn];
      if (l15 == 0) sums[i] = sm;
    }
  }
  __syncthreads();

  // ---- PV: O = P . V  (64x32, K-dim 64 over two mfma) ----
  f32x4 o[4][2] = {};
#pragma unroll
  for (int kk = 0; kk < 2; ++kk) {
    bf16x8 pa[4], bv[2];
#pragma unroll
    for (int fm = 0; fm < 4; ++fm)
      pa[fm] = ldfrag(&P[(fm * 16 + l15) * 72 + kk * 32], l4);
#pragma unroll
    for (int fn = 0; fn < 2; ++fn)
      bv[fn] = ldfrag(&VT[(fn * 16 + l15) * 72 + kk * 32], l4);
#pragma unroll
    for (int fm = 0; fm < 4; ++fm)
#pragma unroll
      for (int fn = 0; fn < 2; ++fn)
        o[fm][fn] = __builtin_amdgcn_mfma_f32_16x16x32_bf16(
            pa[fm], bv[fn], o[fm][fn], 0, 0, 0);
  }
  // ---- normalize by row-sum, write out ----
  u16* ob = outp + (size_t)w * 49 * 384 + h * 32;
#pragma unroll
  for (int fm = 0; fm < 4; ++fm) {
#pragma unroll
    for (int r = 0; r < 4; ++r) {
      const int i = fm * 16 + l4 * 4 + r;
      if (i < 49) {
        const float inv = 1.0f / sums[i];
        ob[(size_t)i * 384 + l15] = f2bf(o[fm][0][r] * inv);
        ob[(size_t)i * 384 + 16 + l15] = f2bf(o[fm][1][r] * inv);
      }
    }
  }
}

// ---------------------------------------------------------------------------
extern "C" void kernel_launch(void* const* d_in, const int* in_sizes, int n_in,
                              void* d_out, int out_size, void* d_ws,
                              size_t ws_size, hipStream_t stream) {
  const float* x      = (const float*)d_in[0];
  const float* n1g    = (const float*)d_in[1];
  const float* n1b    = (const float*)d_in[2];
  const float* qkv_w  = (const float*)d_in[3];
  const float* qkv_b  = (const float*)d_in[4];
  const float* tau    = (const float*)d_in[5];
  const float* proj_w = (const float*)d_in[6];
  const float* proj_b = (const float*)d_in[7];
  const float* c_w1   = (const float*)d_in[8];
  const float* c_b1   = (const float*)d_in[9];
  const float* c_w2   = (const float*)d_in[10];
  const float* c_b2   = (const float*)d_in[11];
  const float* n2g    = (const float*)d_in[12];
  const float* n2b    = (const float*)d_in[13];
  const float* mlp_w1 = (const float*)d_in[14];
  const float* mlp_b1 = (const float*)d_in[15];
  const float* mlp_w2 = (const float*)d_in[16];
  const float* mlp_b2 = (const float*)d_in[17];
  float* out = (float*)d_out;
  char* ws = (char*)d_ws;

  // ws layout (bytes)
  constexpr size_t WS_WT    = 0;          // bf16 weights^T, 3538944 B
  constexpr size_t WS_BIAST = 3538944;    // f32 [12][49][49]
  constexpr size_t WS_XW    = 4194304;    // bf16 [100352][384]  (also ln2)
  constexpr size_t WS_QKV   = 81264640;   // bf16 [100352][1152] (also hidden lo)
  constexpr size_t WS_ATT   = 312475648;  // bf16 [100352][384]  (also hidden hi)
  constexpr size_t WS_NEED  = 389545984;

  if (ws_size < WS_NEED) {  // distinctive sentinel: absmax ~12345 => ws too small
    fill_k<<<(out_size + 255) / 256, 256, 0, stream>>>(out, out_size);
    return;
  }

  u16* wqkvT  = (u16*)(ws + WS_WT);
  u16* wprojT = (u16*)(ws + WS_WT + 884736);
  u16* wm1T   = (u16*)(ws + WS_WT + 1179648);
  u16* wm2T   = (u16*)(ws + WS_WT + 2359296);
  float* biasT = (float*)(ws + WS_BIAST);
  u16* xw  = (u16*)(ws + WS_XW);
  u16* qkv = (u16*)(ws + WS_QKV);
  u16* att = (u16*)(ws + WS_ATT);
  u16* hid = qkv;   // [100352][1536] spans qkv+att regions exactly
  u16* ln2 = xw;

  wconv_k<<<6912, 256, 0, stream>>>(qkv_w, proj_w, mlp_w1, mlp_w2, (u16*)ws);
  biastab_k<<<10, 256, 0, stream>>>(c_w1, c_b1, c_w2, c_b2, biasT);
  ln_k<1><<<25088, 256, 0, stream>>>(x, n1g, n1b, xw);
  gemm_k<0><<<dim3(9, 784), 256, 0, stream>>>(xw, wqkvT, qkv_b, tau, qkv,
                                              100352, 1152, 384);
  attn_k<<<6144, 256, 0, stream>>>(qkv, biasT, att);
  gemm_k<1><<<dim3(3, 784), 256, 0, stream>>>(att, wprojT, proj_b, x, out,
                                              100352, 384, 384);
  ln_k<0><<<25088, 256, 0, stream>>>(out, n2g, n2b, ln2);
  gemm_k<2><<<dim3(12, 784), 256, 0, stream>>>(ln2, wm1T, mlp_b1, nullptr, hid,
                                               100352, 1536, 384);
  gemm_k<3><<<dim3(3, 784), 256, 0, stream>>>(hid, wm2T, mlp_b2, nullptr, out,
                                              100352, 384, 1536);
}

// Round 2
// 1383.256 us; speedup vs baseline: 1.0451x; 1.0451x over previous
//
#include <hip/hip_runtime.h>
#include <cstdint>
#include <cstddef>

// ---------------------------------------------------------------------------
// SwinV2 block, MI355X bf16-MFMA implementation.
// Sizes: B=32, H=W=56, WS=7, N=49, NW=64, HEADS=12, DIM=384, tokens M=100352.
// Round 2: m97-style GEMM staging (global_load_lds width=16) + XCD swizzle.
// ---------------------------------------------------------------------------

typedef unsigned short u16;
typedef __bf16 bf16x8 __attribute__((ext_vector_type(8)));
typedef float f32x4 __attribute__((ext_vector_type(4)));

__device__ __forceinline__ u16 f2bf(float f) {
  unsigned u = __builtin_bit_cast(unsigned, f);
  u += 0x7fffu + ((u >> 16) & 1u);
  return (u16)(u >> 16);
}

// async global->LDS, 16 bytes per lane. lds ptr must be wave-uniform base;
// lane i's 16B land at base + i*16.
__device__ __forceinline__ void gll16(const u16* g, u16* l) {
  __builtin_amdgcn_global_load_lds(
      (const __attribute__((address_space(1))) void*)g,
      (__attribute__((address_space(3))) void*)l, 16, 0, 0);
}

// load one 8-elem MFMA input fragment; rowp = &LDS[row*ld + k_base], l4 = lane>>4
__device__ __forceinline__ bf16x8 ldfrag(const u16* rowp, int l4) {
  return *(const bf16x8*)(rowp + 8 * l4);
}

// ---------------- diagnostics: ws too small sentinel ----------------
__global__ __launch_bounds__(256) void fill_k(float* o, int n) {
  int i = blockIdx.x * 256 + threadIdx.x;
  if (i < n) o[i] = 12345.0f;
}

// ---------------- weight convert + transpose (fp32 [K][N] -> bf16 [N][K]) ----
__global__ __launch_bounds__(256) void wconv_k(
    const float* __restrict__ qkv_w, const float* __restrict__ proj_w,
    const float* __restrict__ mlp_w1, const float* __restrict__ mlp_w2,
    u16* __restrict__ o) {
  const int id = blockIdx.x * 256 + threadIdx.x;  // grid covers exactly 1769472
  if (id < 442368) {                // qkv_w (384,1152) -> [1152][384]
    const int n = id / 384, k = id - n * 384;
    o[id] = f2bf(qkv_w[k * 1152 + n]);
  } else if (id < 589824) {         // proj_w (384,384) -> [384][384]
    const int e = id - 442368; const int n = e / 384, k = e - n * 384;
    o[id] = f2bf(proj_w[k * 384 + n]);
  } else if (id < 1179648) {        // mlp_w1 (384,1536) -> [1536][384]
    const int e = id - 589824; const int n = e / 384, k = e - n * 384;
    o[id] = f2bf(mlp_w1[k * 1536 + n]);
  } else {                          // mlp_w2 (1536,384) -> [384][1536]
    const int e = id - 1179648; const int n = e / 1536, k = e - n * 1536;
    o[id] = f2bf(mlp_w2[k * 384 + n]);
  }
}

// ---------------- continuous relative position bias table -------------------
__global__ __launch_bounds__(256) void biastab_k(
    const float* __restrict__ w1, const float* __restrict__ b1,
    const float* __restrict__ w2, const float* __restrict__ b2,
    float* __restrict__ biasT) {
  const int id = blockIdx.x * 256 + threadIdx.x;
  if (id >= 2401) return;
  const int i = id / 49, j = id - i * 49;
  const int r1 = i / 7, c1 = i - r1 * 7, r2 = j / 7, c2 = j - r2 * 7;
  float dy = (float)(r1 - r2), dx = (float)(c1 - c2);
  dy = copysignf(log1pf(fabsf(dy)), dy);
  dx = copysignf(log1pf(fabsf(dx)), dx);
  float accv[12];
#pragma unroll
  for (int t = 0; t < 12; ++t) accv[t] = b2[t];
  for (int u = 0; u < 64; ++u) {
    float hu = fmaxf(dy * w1[u] + dx * w1[64 + u] + b1[u], 0.0f);
#pragma unroll
    for (int t = 0; t < 12; ++t) accv[t] += hu * w2[u * 12 + t];
  }
#pragma unroll
  for (int t = 0; t < 12; ++t) biasT[t * 2401 + id] = accv[t];
}

// ---------------- LayerNorm (one wave per token), optional shift+window map --
template <int WINMAP>
__global__ __launch_bounds__(256, 4) void ln_k(
    const float* __restrict__ X, const float* __restrict__ g,
    const float* __restrict__ b, u16* __restrict__ O) {
  const int t = blockIdx.x * 4 + (threadIdx.x >> 6);
  const int lane = threadIdx.x & 63;
  const float* xr = X + (size_t)t * 384;
  float v[6];
  float s = 0.f;
#pragma unroll
  for (int i = 0; i < 6; ++i) { v[i] = xr[lane + i * 64]; s += v[i]; }
#pragma unroll
  for (int m = 1; m < 64; m <<= 1) s += __shfl_xor(s, m);
  const float mu = s * (1.0f / 384.0f);
  float q = 0.f;
#pragma unroll
  for (int i = 0; i < 6; ++i) { float d = v[i] - mu; q += d * d; }
#pragma unroll
  for (int m = 1; m < 64; m <<= 1) q += __shfl_xor(q, m);
  const float rstd = rsqrtf(q * (1.0f / 384.0f) + 1e-5f);
  size_t row;
  if constexpr (WINMAP) {
    const int bb = t / 3136, hw = t - bb * 3136;
    const int ho = hw / 56, wo = hw - ho * 56;
    int hs = ho - 3; if (hs < 0) hs += 56;
    int ws2 = wo - 3; if (ws2 < 0) ws2 += 56;
    const int h7 = hs / 7, w7 = ws2 / 7;
    const int wwin = bb * 64 + h7 * 8 + w7;
    const int p = (hs - h7 * 7) * 7 + (ws2 - w7 * 7);
    row = (size_t)wwin * 49 + p;
  } else {
    row = (size_t)t;
  }
  u16* orow = O + row * 384;
#pragma unroll
  for (int i = 0; i < 6; ++i) {
    const int d = lane + i * 64;
    orow[d] = f2bf((v[i] - mu) * rstd * g[d] + b[d]);
  }
}

// ---------------- 128x128 bf16 MFMA GEMM, global_load_lds staging ------------
// A [M][K] bf16 row-major, Bt [N][K] bf16 row-major (i.e. W transposed).
// EPI 0: qkv   (bias add, q/k head L2-norm, tau fold into q) -> bf16 out
// EPI 1: proj  (bias + residual x + window-reverse/unshift)  -> f32 d_out
// EPI 2: mlp1  (bias + exact gelu)                           -> bf16 out
// EPI 3: mlp2  (bias, accumulate into d_out)                 -> f32 +=
template <int EPI>
__global__ __launch_bounds__(256, 2) void gemm_k(
    const u16* __restrict__ A, const u16* __restrict__ Bt,
    const float* __restrict__ bias, const float* __restrict__ aux,
    void* __restrict__ outp, int M, int N, int K) {
  __shared__ u16 Ash[128 * 32];
  __shared__ u16 Bsh[128 * 32];
  const int tid = threadIdx.x;
  const int lane = tid & 63;
  const int wv = tid >> 6;
  const int wrow = wv >> 1, wcol = wv & 1;
  const int l15 = lane & 15, l4 = lane >> 4;

  // XCD-chunked swizzle (all launches have nwg % 8 == 0): consecutive tiles
  // (sharing the A row-panel) stay on one XCD's L2.
  const int nx = gridDim.x;
  const int nwg = nx * gridDim.y;
  int bid = blockIdx.y * nx + blockIdx.x;
  bid = (bid & 7) * (nwg >> 3) + (bid >> 3);
  const int tileN = (bid % nx) * 128;
  const int tileM = (bid / nx) * 128;

  f32x4 acc[4][4] = {};

  // staging map: identical LDS image to a [128][32] row-major tile.
  // wave wv, issue it in {0,1}: lane's 16B -> rows (it*4+wv)*16 + lane/4,
  // cols (lane&3)*8.
  const int r0 = wv * 16 + (lane >> 2);
  const int c0 = (lane & 3) * 8;
  const u16* Ag = A + (size_t)(tileM + r0) * K + c0;
  const u16* Bg = Bt + (size_t)(tileN + r0) * K + c0;
  const size_t rowskip = (size_t)64 * K;
  u16* Al0 = &Ash[wv * 512];
  u16* Al1 = &Ash[(4 + wv) * 512];
  u16* Bl0 = &Bsh[wv * 512];
  u16* Bl1 = &Bsh[(4 + wv) * 512];

  for (int k0 = 0; k0 < K; k0 += 32) {
    __syncthreads();                 // prior iteration's ds_reads complete
    gll16(Ag + k0, Al0);
    gll16(Ag + rowskip + k0, Al1);
    gll16(Bg + k0, Bl0);
    gll16(Bg + rowskip + k0, Bl1);
    __syncthreads();                 // vmcnt(0) drain -> staged data visible
    bf16x8 af[4], bfr[4];
#pragma unroll
    for (int f = 0; f < 4; ++f) {
      af[f] = ldfrag(&Ash[(wrow * 64 + f * 16 + l15) * 32], l4);
      bfr[f] = ldfrag(&Bsh[(wcol * 64 + f * 16 + l15) * 32], l4);
    }
#pragma unroll
    for (int fm = 0; fm < 4; ++fm)
#pragma unroll
      for (int fn = 0; fn < 4; ++fn)
        acc[fm][fn] = __builtin_amdgcn_mfma_f32_16x16x32_bf16(
            af[fm], bfr[fn], acc[fm][fn], 0, 0, 0);
  }

  const int baseRow = tileM + wrow * 64;
  const int baseCol = tileN + wcol * 64;

  if constexpr (EPI == 0) {
    u16* O = (u16*)outp;
#pragma unroll
    for (int fm = 0; fm < 4; ++fm) {
#pragma unroll
      for (int hp = 0; hp < 2; ++hp) {
        const int c0e = baseCol + hp * 32;
        const int seg = c0e >> 5;            // 0..11 q, 12..23 k, 24..35 v
        const bool nrm = seg < 24;
        const float tfac = (seg < 12) ? aux[seg] : 1.0f;
        const float b0 = bias[c0e + l15];
        const float b1 = bias[c0e + 16 + l15];
#pragma unroll
        for (int r = 0; r < 4; ++r) {
          float v0 = acc[fm][2 * hp][r] + b0;
          float v1 = acc[fm][2 * hp + 1][r] + b1;
          if (nrm) {
            float ss = v0 * v0 + v1 * v1;
            ss += __shfl_xor(ss, 1);
            ss += __shfl_xor(ss, 2);
            ss += __shfl_xor(ss, 4);
            ss += __shfl_xor(ss, 8);
            const float f = tfac / fmaxf(sqrtf(ss), 1e-12f);
            v0 *= f; v1 *= f;
          }
          const size_t row = (size_t)(baseRow + fm * 16 + l4 * 4 + r);
          O[row * N + c0e + l15] = f2bf(v0);
          O[row * N + c0e + 16 + l15] = f2bf(v1);
        }
      }
    }
  } else if constexpr (EPI == 1) {
    float* O = (float*)outp;
    const float* X = aux;
#pragma unroll
    for (int fm = 0; fm < 4; ++fm) {
#pragma unroll
      for (int r = 0; r < 4; ++r) {
        const int row = baseRow + fm * 16 + l4 * 4 + r;
        const int w = row / 49, p = row - w * 49;
        const int bb = w >> 6, widx = w & 63;
        const int p7 = p / 7;
        int hs = (widx >> 3) * 7 + p7;
        int ws2 = (widx & 7) * 7 + (p - p7 * 7);
        int ho = hs + 3; if (ho >= 56) ho -= 56;
        int wo = ws2 + 3; if (wo >= 56) wo -= 56;
        const size_t tok = (size_t)bb * 3136 + ho * 56 + wo;
#pragma unroll
        for (int fn = 0; fn < 4; ++fn) {
          const int col = baseCol + fn * 16 + l15;
          O[tok * 384 + col] = X[tok * 384 + col] + acc[fm][fn][r] + bias[col];
        }
      }
    }
  } else if constexpr (EPI == 2) {
    u16* O = (u16*)outp;
#pragma unroll
    for (int fm = 0; fm < 4; ++fm) {
#pragma unroll
      for (int fn = 0; fn < 4; ++fn) {
        const int col = baseCol + fn * 16 + l15;
        const float bc = bias[col];
#pragma unroll
        for (int r = 0; r < 4; ++r) {
          const size_t row = (size_t)(baseRow + fm * 16 + l4 * 4 + r);
          const float v = acc[fm][fn][r] + bc;
          const float g = 0.5f * v * (1.0f + erff(v * 0.70710678118654752f));
          O[row * N + col] = f2bf(g);
        }
      }
    }
  } else {
    float* O = (float*)outp;
#pragma unroll
    for (int fm = 0; fm < 4; ++fm) {
#pragma unroll
      for (int fn = 0; fn < 4; ++fn) {
        const int col = baseCol + fn * 16 + l15;
        const float bc = bias[col];
#pragma unroll
        for (int r = 0; r < 4; ++r) {
          const size_t row = (size_t)(baseRow + fm * 16 + l4 * 4 + r);
          O[row * N + col] += acc[fm][fn][r] + bc;
        }
      }
    }
  }
}

// ---------------- attention: one wave per (window, head) ---------------------
__global__ __launch_bounds__(256, 2) void attn_k(
    const u16* __restrict__ qkv, const float* __restrict__ biasT,
    u16* __restrict__ outp) {
  __shared__ u16 lds[4][7552];
  const int tid = threadIdx.x, lane = tid & 63, wid = tid >> 6;
  const int l15 = lane & 15, l4 = lane >> 4;
  const int W = blockIdx.x * 4 + wid;
  const int w = W / 12, h = W - w * 12;
  u16* S = lds[wid];
  u16* Q = S;
  u16* Kl = S + 2560;
  u16* P = S;
  u16* VT = S + 5120;
  float* sums = (float*)(S + 7424);
  const u16* base = qkv + (size_t)w * 56448 + h * 32;  // 49*1152
  const int widx = w & 63, wh = widx >> 3, ww = widx & 7;
  const bool masked = (wh == 7) || (ww == 7);

#pragma unroll
  for (int it = 0; it < 4; ++it) {
    const int row = it * 16 + (lane >> 2);
    const int c8 = (lane & 3) * 8;
    uint4 qv = {0, 0, 0, 0}, kv = {0, 0, 0, 0};
    if (row < 49) {
      qv = *(const uint4*)(base + (size_t)row * 1152 + c8);
      kv = *(const uint4*)(base + (size_t)row * 1152 + 384 + c8);
    }
    *(uint4*)&Q[row * 40 + c8] = qv;
    *(uint4*)&Kl[row * 40 + c8] = kv;
  }
  {
    const int d = lane & 31;
    const int jh = lane >> 5;
#pragma unroll 4
    for (int jt = 0; jt < 32; ++jt) {
      const int j = jt * 2 + jh;
      u16 val = 0;
      if (j < 49) val = base[(size_t)j * 1152 + 768 + d];
      VT[d * 72 + j] = val;
    }
  }
  __syncthreads();

  f32x4 sc[4][4] = {};
  {
    bf16x8 aq[4], bk[4];
#pragma unroll
    for (int f = 0; f < 4; ++f) aq[f] = ldfrag(&Q[(f * 16 + l15) * 40], l4);
#pragma unroll
    for (int f = 0; f < 4; ++f) bk[f] = ldfrag(&Kl[(f * 16 + l15) * 40], l4);
#pragma unroll
    for (int fm = 0; fm < 4; ++fm)
#pragma unroll
      for (int fn = 0; fn < 4; ++fn)
        sc[fm][fn] = __builtin_amdgcn_mfma_f32_16x16x32_bf16(
            aq[fm], bk[fn], sc[fm][fn], 0, 0, 0);
  }
  __syncthreads();  // Q/K reads complete before P overlays them

  int codej[4] = {0, 0, 0, 0};
  if (masked) {
#pragma unroll
    for (int fn = 0; fn < 4; ++fn) {
      const int j = fn * 16 + l15;
      const int pr = j / 7, pc = j - pr * 7;
      const int rr2 = (wh == 7) ? ((pr < 4) ? 1 : 2) : 0;
      const int cc2 = (ww == 7) ? ((pc < 4) ? 1 : 2) : 0;
      codej[fn] = rr2 * 3 + cc2;
    }
  }
#pragma unroll
  for (int fm = 0; fm < 4; ++fm) {
#pragma unroll
    for (int r = 0; r < 4; ++r) {
      const int i = fm * 16 + l4 * 4 + r;
      const bool iok = i < 49;
      int ci = 0;
      if (masked && iok) {
        const int pr = i / 7, pc = i - pr * 7;
        const int rr2 = (wh == 7) ? ((pr < 4) ? 1 : 2) : 0;
        const int cc2 = (ww == 7) ? ((pc < 4) ? 1 : 2) : 0;
        ci = rr2 * 3 + cc2;
      }
      const float* brow = biasT + (size_t)h * 2401 + (iok ? i : 0) * 49;
      float sv[4];
#pragma unroll
      for (int fn = 0; fn < 4; ++fn) {
        const int j = fn * 16 + l15;
        float s = sc[fm][fn][r];
        if (iok && j < 49) {
          s += brow[j];
          if (masked && codej[fn] != ci) s -= 100.0f;
        } else {
          s = -1e30f;
        }
        sv[fn] = s;
      }
      float mx = fmaxf(fmaxf(sv[0], sv[1]), fmaxf(sv[2], sv[3]));
      mx = fmaxf(mx, __shfl_xor(mx, 1));
      mx = fmaxf(mx, __shfl_xor(mx, 2));
      mx = fmaxf(mx, __shfl_xor(mx, 4));
      mx = fmaxf(mx, __shfl_xor(mx, 8));
      float sm = 0.f;
      u16 pb[4];
#pragma unroll
      for (int fn = 0; fn < 4; ++fn) {
        const float e = __expf(sv[fn] - mx);
        sm += e;
        pb[fn] = f2bf(e);
      }
      sm += __shfl_xor(sm, 1);
      sm += __shfl_xor(sm, 2);
      sm += __shfl_xor(sm, 4);
      sm += __shfl_xor(sm, 8);
#pragma unroll
      for (int fn = 0; fn < 4; ++fn) P[i * 72 + fn * 16 + l15] = pb[fn];
      if (l15 == 0) sums[i] = sm;
    }
  }
  __syncthreads();

  f32x4 o[4][2] = {};
#pragma unroll
  for (int kk = 0; kk < 2; ++kk) {
    bf16x8 pa[4], bv[2];
#pragma unroll
    for (int fm = 0; fm < 4; ++fm)
      pa[fm] = ldfrag(&P[(fm * 16 + l15) * 72 + kk * 32], l4);
#pragma unroll
    for (int fn = 0; fn < 2; ++fn)
      bv[fn] = ldfrag(&VT[(fn * 16 + l15) * 72 + kk * 32], l4);
#pragma unroll
    for (int fm = 0; fm < 4; ++fm)
#pragma unroll
      for (int fn = 0; fn < 2; ++fn)
        o[fm][fn] = __builtin_amdgcn_mfma_f32_16x16x32_bf16(
            pa[fm], bv[fn], o[fm][fn], 0, 0, 0);
  }
  u16* ob = outp + (size_t)w * 49 * 384 + h * 32;
#pragma unroll
  for (int fm = 0; fm < 4; ++fm) {
#pragma unroll
    for (int r = 0; r < 4; ++r) {
      const int i = fm * 16 + l4 * 4 + r;
      if (i < 49) {
        const float inv = 1.0f / sums[i];
        ob[(size_t)i * 384 + l15] = f2bf(o[fm][0][r] * inv);
        ob[(size_t)i * 384 + 16 + l15] = f2bf(o[fm][1][r] * inv);
      }
    }
  }
}

// ---------------------------------------------------------------------------
extern "C" void kernel_launch(void* const* d_in, const int* in_sizes, int n_in,
                              void* d_out, int out_size, void* d_ws,
                              size_t ws_size, hipStream_t stream) {
  const float* x      = (const float*)d_in[0];
  const float* n1g    = (const float*)d_in[1];
  const float* n1b    = (const float*)d_in[2];
  const float* qkv_w  = (const float*)d_in[3];
  const float* qkv_b  = (const float*)d_in[4];
  const float* tau    = (const float*)d_in[5];
  const float* proj_w = (const float*)d_in[6];
  const float* proj_b = (const float*)d_in[7];
  const float* c_w1   = (const float*)d_in[8];
  const float* c_b1   = (const float*)d_in[9];
  const float* c_w2   = (const float*)d_in[10];
  const float* c_b2   = (const float*)d_in[11];
  const float* n2g    = (const float*)d_in[12];
  const float* n2b    = (const float*)d_in[13];
  const float* mlp_w1 = (const float*)d_in[14];
  const float* mlp_b1 = (const float*)d_in[15];
  const float* mlp_w2 = (const float*)d_in[16];
  const float* mlp_b2 = (const float*)d_in[17];
  float* out = (float*)d_out;
  char* ws = (char*)d_ws;

  // ws layout (bytes)
  constexpr size_t WS_WT    = 0;          // bf16 weights^T, 3538944 B
  constexpr size_t WS_BIAST = 3538944;    // f32 [12][49][49]
  constexpr size_t WS_XW    = 4194304;    // bf16 [100352][384]  (also ln2)
  constexpr size_t WS_QKV   = 81264640;   // bf16 [100352][1152] (also hidden lo)
  constexpr size_t WS_ATT   = 312475648;  // bf16 [100352][384]  (also hidden hi)
  constexpr size_t WS_NEED  = 389545984;

  if (ws_size < WS_NEED) {  // distinctive sentinel: absmax ~12345 => ws too small
    fill_k<<<(out_size + 255) / 256, 256, 0, stream>>>(out, out_size);
    return;
  }

  u16* wqkvT  = (u16*)(ws + WS_WT);
  u16* wprojT = (u16*)(ws + WS_WT + 884736);
  u16* wm1T   = (u16*)(ws + WS_WT + 1179648);
  u16* wm2T   = (u16*)(ws + WS_WT + 2359296);
  float* biasT = (float*)(ws + WS_BIAST);
  u16* xw  = (u16*)(ws + WS_XW);
  u16* qkv = (u16*)(ws + WS_QKV);
  u16* att = (u16*)(ws + WS_ATT);
  u16* hid = qkv;   // [100352][1536] spans qkv+att regions exactly
  u16* ln2 = xw;

  wconv_k<<<6912, 256, 0, stream>>>(qkv_w, proj_w, mlp_w1, mlp_w2, (u16*)ws);
  biastab_k<<<10, 256, 0, stream>>>(c_w1, c_b1, c_w2, c_b2, biasT);
  ln_k<1><<<25088, 256, 0, stream>>>(x, n1g, n1b, xw);
  gemm_k<0><<<dim3(9, 784), 256, 0, stream>>>(xw, wqkvT, qkv_b, tau, qkv,
                                              100352, 1152, 384);
  attn_k<<<6144, 256, 0, stream>>>(qkv, biasT, att);
  gemm_k<1><<<dim3(3, 784), 256, 0, stream>>>(att, wprojT, proj_b, x, out,
                                              100352, 384, 384);
  ln_k<0><<<25088, 256, 0, stream>>>(out, n2g, n2b, ln2);
  gemm_k<2><<<dim3(12, 784), 256, 0, stream>>>(ln2, wm1T, mlp_b1, nullptr, hid,
                                               100352, 1536, 384);
  gemm_k<3><<<dim3(3, 784), 256, 0, stream>>>(hid, wm2T, mlp_b2, nullptr, out,
                                              100352, 384, 1536);
}